// Round 6
// baseline (3087.014 us; speedup 1.0000x reference)
//
#include <hip/hip_runtime.h>
#include <hip/hip_bf16.h>

#define N_NODES 100000
#define N_EDGES 1600000

using bf16 = __hip_bfloat16;
typedef unsigned int u32;

static __device__ __forceinline__ float b2f(bf16 v){ return __bfloat162float(v); }

// float loader: f32m=1 -> buffer is float32, f32m=0 -> buffer is bf16
static __device__ __forceinline__ float ldf(const void* p, long i, int f32m){
  return f32m ? ((const float*)p)[i] : b2f(((const bf16*)p)[i]);
}

// ---------------- dtype detection (device-side, deterministic) ----------------
// floats: if buffer is f32, the low 16 bits of each word are mantissa garbage ->
// viewed as bf16 they have wild exponents. If buffer is bf16, every half is a
// sane value (x ~ N(0,1)). ints: if int64, odd 32-bit words are all zero
// (indices < 2^17); if int32 they are random indices (nonzero w.p. 1-1e-5).
__global__ void k_detect(const u32* __restrict__ xw, const int* __restrict__ eiw,
                         int* __restrict__ flags){
  __shared__ int s_wild, s_nzodd;
  if(threadIdx.x==0){ s_wild=0; s_nzodd=0; }
  __syncthreads();
  int wild=0, nz=0;
  for(int k=threadIdx.x;k<2048;k+=256){
    u32 w  = xw[k];
    u32 lo = w & 0xffffu;
    int e  = (int)((lo>>7)&0xffu);
    if((lo & 0x7fffu)!=0u && (e<90 || e>160)) wild++;
    if(eiw[2*k+1]!=0) nz++;
  }
  atomicAdd(&s_wild, wild);
  atomicAdd(&s_nzodd, nz);
  __syncthreads();
  if(threadIdx.x==0){
    flags[0] = (s_wild > 512) ? 1 : 0;   // 1: floats are f32
    flags[1] = (s_nzodd == 0) ? 1 : 0;   // 1: indices are int64
  }
}

__global__ void k_zero2(int* __restrict__ a, int* __restrict__ b){
  int i = blockIdx.x*256 + threadIdx.x;
  if(i<N_NODES){ a[i]=0; b[i]=0; }
}

// ---------------- CSR build ----------------

__global__ void k_count(const int* __restrict__ ei, const int* __restrict__ flags,
                        int* __restrict__ deg){
  int e = blockIdx.x*256 + threadIdx.x;
  int i64 = flags[1];
  if(e < N_EDGES){
    long di = i64 ? 2l*(N_EDGES + e) : (long)(N_EDGES + e);
    atomicAdd(&deg[ei[di]], 1);
  }
}

__global__ void k_scan(const int* __restrict__ deg, int* __restrict__ off){
  __shared__ int sums[1024];
  __shared__ int base[1025];
  int t = threadIdx.x;
  const int chunk = (N_NODES + 1023)/1024;
  int b0 = t*chunk, b1 = min(b0+chunk, N_NODES);
  int s = 0;
  for(int i=b0;i<b1;i++) s += deg[i];
  sums[t] = s;
  __syncthreads();
  if(t==0){
    int acc=0;
    for(int i=0;i<1024;i++){ base[i]=acc; acc+=sums[i]; }
    base[1024]=acc;
  }
  __syncthreads();
  int acc = base[t];
  for(int i=b0;i<b1;i++){ off[i]=acc; acc+=deg[i]; }
  if(t==0) off[N_NODES] = base[1024];
}

__global__ void k_fill(const int* __restrict__ ei, const void* __restrict__ ew,
                       const int* __restrict__ flags, const int* __restrict__ off,
                       int* __restrict__ cur, int* __restrict__ csr_src,
                       float* __restrict__ csr_ew){
  int e = blockIdx.x*256 + threadIdx.x;
  int i64 = flags[1], f32m = flags[0];
  if(e < N_EDGES){
    int s = ei[i64 ? 2l*e : (long)e];
    int d = ei[i64 ? 2l*(N_EDGES+e) : (long)(N_EDGES+e)];
    int p = atomicAdd(&cur[d], 1);
    int idx = off[d] + p;
    csr_src[idx] = s;
    csr_ew[idx]  = ldf(ew, e, f32m);
  }
}

// ---------------- embedding: h0 = relu(x @ W + b), [100k,100]x[100,80] ----------------

__global__ __launch_bounds__(256) void k_embed(const void* __restrict__ x,
                                               const void* __restrict__ W,
                                               const void* __restrict__ b,
                                               const int* __restrict__ flags,
                                               float* __restrict__ h){
  __shared__ float Ws[100*80];
  const int f32m = flags[0];
  for(int i=threadIdx.x;i<100*80;i+=256) Ws[i]=ldf(W,i,f32m);
  __syncthreads();
  long tid = (long)blockIdx.x*256 + threadIdx.x;   // exactly N_NODES*80 threads
  int i = (int)(tid/80), k = (int)(tid%80);
  float acc = ldf(b,k,f32m);
  #pragma unroll 4
  for(int c=0;c<100;c++) acc = fmaf(ldf(x,(long)i*100+c,f32m), Ws[c*80+k], acc);
  h[(long)i*80+k] = fmaxf(acc, 0.f);
}

// ---------------- fused SAGE layer ----------------
// one wave per node: gather+mean over CSR edges, matvec (agg@Wl + h@Wr + b),
// L2 normalize, optional relu, store.

template<int CIN, int COUT, bool LAST>
__global__ __launch_bounds__(256) void k_sage(
    const float* __restrict__ hin, const int* __restrict__ off,
    const int* __restrict__ csr_src, const float* __restrict__ csr_ew,
    const void* __restrict__ Wl, const void* __restrict__ Wr, const void* __restrict__ bias,
    const int* __restrict__ flags, float* __restrict__ hout, void* __restrict__ outp)
{
  __shared__ float Wls[CIN*COUT];
  __shared__ float Wrs[CIN*COUT];
  __shared__ float rows[4][2*CIN];
  const int f32m = flags[0];
  for(int i=threadIdx.x;i<CIN*COUT;i+=256){ Wls[i]=ldf(Wl,i,f32m); Wrs[i]=ldf(Wr,i,f32m); }
  __syncthreads();

  const int wave = threadIdx.x>>6, lane = threadIdx.x&63;
  const int node = blockIdx.x*4 + wave;              // grid covers N_NODES exactly
  constexpr int NC = (CIN+63)/64;                    // 1 (64ch) or 2 (80ch)

  float hreg[NC], acc[NC];
  const float* hr = hin + (long)node*CIN;
  #pragma unroll
  for(int u=0;u<NC;u++){
    int c = lane + 64*u;
    hreg[u] = (c<CIN) ? hr[c] : 0.f;
    acc[u]  = 0.f;
  }

  const int e0 = off[node], e1 = off[node+1];
  for(int e=e0;e<e1;e++){
    int s = csr_src[e];
    float w = LAST ? 1.f : csr_ew[e];
    const float* sr = hin + (long)s*CIN;
    #pragma unroll
    for(int u=0;u<NC;u++){
      int c = lane + 64*u;
      if(c<CIN) acc[u] = fmaf(w, sr[c], acc[u]);
    }
  }

  const float inv = 1.f/fmaxf((float)(e1-e0), 1.f);
  float* aggs = rows[wave];
  float* hs   = rows[wave]+CIN;
  #pragma unroll
  for(int u=0;u<NC;u++){
    int c = lane + 64*u;
    if(c<CIN){ aggs[c]=acc[u]*inv; hs[c]=hreg[u]; }
  }
  __syncthreads();   // safe: every thread reaches (grid covers nodes exactly)

  float o = 0.f;
  if(lane<COUT){
    o = ldf(bias,lane,f32m);
    for(int c=0;c<CIN;c++){
      o = fmaf(aggs[c], Wls[c*COUT+lane], o);
      o = fmaf(hs[c],   Wrs[c*COUT+lane], o);
    }
  }

  float sq = o*o;                       // lanes >= COUT contribute 0
  #pragma unroll
  for(int d=1; d<64; d<<=1) sq += __shfl_xor(sq, d);
  float r = o * (1.f/fmaxf(sqrtf(sq), 1e-12f));
  if(!LAST) r = fmaxf(r, 0.f);

  if(lane<COUT){
    long oi = (long)node*COUT+lane;
    if(LAST){
      if(f32m) ((float*)outp)[oi] = r;
      else     ((bf16*)outp)[oi]  = __float2bfloat16(r);
    } else {
      hout[oi] = r;
    }
  }
}

// ---------------- launch ----------------

extern "C" void kernel_launch(void* const* d_in, const int* in_sizes, int n_in,
                              void* d_out, int out_size, void* d_ws, size_t ws_size,
                              hipStream_t stream){
  const void* x    = d_in[0];
  const int*  ei   = (const int*)d_in[1];
  const void* ew   = d_in[2];
  const void* embW = d_in[3];
  const void* embB = d_in[4];
  const void *Wl0=d_in[5],  *Wr0=d_in[6],  *b0=d_in[7];
  const void *Wl1=d_in[8],  *Wr1=d_in[9],  *b1=d_in[10];
  const void *Wl2=d_in[11], *Wr2=d_in[12], *b2=d_in[13];
  const void *Wl3=d_in[14], *Wr3=d_in[15], *b3=d_in[16];
  const void *Wlo=d_in[17], *Wro=d_in[18], *bo=d_in[19];

  char* w = (char*)d_ws;
  int*   flags   = (int*)w;   w += 16;
  int*   deg     = (int*)w;   w += (size_t)N_NODES*4;
  int*   cur     = (int*)w;   w += (size_t)N_NODES*4;
  int*   off     = (int*)w;   w += (size_t)(N_NODES+1)*4 + 4;
  int*   csr_src = (int*)w;   w += (size_t)N_EDGES*4;
  float* csr_ew  = (float*)w; w += (size_t)N_EDGES*4;
  float* hA      = (float*)w; w += (size_t)N_NODES*80*4;   // 80-wide for layer0 in, 64-wide reuse later
  float* hB      = (float*)w;                              // 64-wide

  k_detect<<<1, 256, 0, stream>>>((const u32*)x, ei, flags);
  k_zero2<<<(N_NODES+255)/256, 256, 0, stream>>>(deg, cur);
  k_count<<<N_EDGES/256, 256, 0, stream>>>(ei, flags, deg);
  k_scan <<<1, 1024, 0, stream>>>(deg, off);
  k_fill <<<N_EDGES/256, 256, 0, stream>>>(ei, ew, flags, off, cur, csr_src, csr_ew);

  k_embed<<<(N_NODES*80)/256, 256, 0, stream>>>(x, embW, embB, flags, hA);

  k_sage<80,64,false><<<N_NODES/4, 256, 0, stream>>>(hA, off, csr_src, csr_ew, Wl0, Wr0, b0, flags, hB, nullptr);
  k_sage<64,64,false><<<N_NODES/4, 256, 0, stream>>>(hB, off, csr_src, csr_ew, Wl1, Wr1, b1, flags, hA, nullptr);
  k_sage<64,64,false><<<N_NODES/4, 256, 0, stream>>>(hA, off, csr_src, csr_ew, Wl2, Wr2, b2, flags, hB, nullptr);
  k_sage<64,64,false><<<N_NODES/4, 256, 0, stream>>>(hB, off, csr_src, csr_ew, Wl3, Wr3, b3, flags, hA, nullptr);
  k_sage<64,18,true ><<<N_NODES/4, 256, 0, stream>>>(hA, off, csr_src, csr_ew, Wlo, Wro, bo, flags, nullptr, d_out);
}

// Round 7
// 1606.798 us; speedup vs baseline: 1.9212x; 1.9212x over previous
//
#include <hip/hip_runtime.h>
#include <hip/hip_bf16.h>

#define N_NODES 100000
#define N_EDGES 1600000

using bf16 = __hip_bfloat16;
typedef unsigned int u32;

static __device__ __forceinline__ float b2f(bf16 v){ return __bfloat162float(v); }

// float loader: f32m=1 -> buffer is float32, f32m=0 -> buffer is bf16
static __device__ __forceinline__ float ldf(const void* p, long i, int f32m){
  return f32m ? ((const float*)p)[i] : b2f(((const bf16*)p)[i]);
}

static __device__ __forceinline__ u32 f2bf_rne(float f){
  u32 b = __float_as_uint(f);
  return (b + 0x7fffu + ((b>>16)&1u)) >> 16;
}

// ---------------- dtype detection (device-side, deterministic) ----------------
__global__ void k_detect(const u32* __restrict__ xw, const int* __restrict__ eiw,
                         int* __restrict__ flags){
  __shared__ int s_wild, s_nzodd;
  if(threadIdx.x==0){ s_wild=0; s_nzodd=0; }
  __syncthreads();
  int wild=0, nz=0;
  for(int k=threadIdx.x;k<2048;k+=256){
    u32 w  = xw[k];
    u32 lo = w & 0xffffu;
    int e  = (int)((lo>>7)&0xffu);
    if((lo & 0x7fffu)!=0u && (e<90 || e>160)) wild++;
    if(eiw[2*k+1]!=0) nz++;
  }
  atomicAdd(&s_wild, wild);
  atomicAdd(&s_nzodd, nz);
  __syncthreads();
  if(threadIdx.x==0){
    flags[0] = (s_wild > 512) ? 1 : 0;   // 1: floats are f32
    flags[1] = (s_nzodd == 0) ? 1 : 0;   // 1: indices are int64
  }
}

__global__ void k_zero2(int* __restrict__ a, int* __restrict__ b){
  int i = blockIdx.x*256 + threadIdx.x;
  if(i<N_NODES){ a[i]=0; b[i]=0; }
}

// ---------------- CSR build ----------------

__global__ void k_count(const int* __restrict__ ei, const int* __restrict__ flags,
                        int* __restrict__ deg){
  int e = blockIdx.x*256 + threadIdx.x;
  int i64 = flags[1];
  if(e < N_EDGES){
    long di = i64 ? 2l*(N_EDGES + e) : (long)(N_EDGES + e);
    atomicAdd(&deg[ei[di]], 1);
  }
}

__global__ void k_scan(const int* __restrict__ deg, int* __restrict__ off){
  __shared__ int sums[1024];
  __shared__ int base[1025];
  int t = threadIdx.x;
  const int chunk = (N_NODES + 1023)/1024;
  int b0 = t*chunk, b1 = min(b0+chunk, N_NODES);
  int s = 0;
  for(int i=b0;i<b1;i++) s += deg[i];
  sums[t] = s;
  __syncthreads();
  if(t==0){
    int acc=0;
    for(int i=0;i<1024;i++){ base[i]=acc; acc+=sums[i]; }
    base[1024]=acc;
  }
  __syncthreads();
  int acc = base[t];
  for(int i=b0;i<b1;i++){ off[i]=acc; acc+=deg[i]; }
  if(t==0) off[N_NODES] = base[1024];
}

__global__ void k_fill(const int* __restrict__ ei, const void* __restrict__ ew,
                       const int* __restrict__ flags, const int* __restrict__ off,
                       int* __restrict__ cur, int* __restrict__ csr_src,
                       float* __restrict__ csr_ew){
  int e = blockIdx.x*256 + threadIdx.x;
  int i64 = flags[1], f32m = flags[0];
  if(e < N_EDGES){
    int s = ei[i64 ? 2l*e : (long)e];
    int d = ei[i64 ? 2l*(N_EDGES+e) : (long)(N_EDGES+e)];
    int p = atomicAdd(&cur[d], 1);
    int idx = off[d] + p;
    csr_src[idx] = s;
    csr_ew[idx]  = ldf(ew, e, f32m);
  }
}

// ---------------- weight pre-pack: out[c*64+k] = {bf16(Wr), bf16(Wl)} ----------------

__global__ void k_pack(const void* __restrict__ Wl, const void* __restrict__ Wr,
                       const int* __restrict__ flags, int CIN, int COUT,
                       u32* __restrict__ out){
  int i = blockIdx.x*256 + threadIdx.x;
  if(i < CIN*64){
    int c = i>>6, k = i&63;
    u32 v = 0;
    if(k < COUT){
      int f32m = flags[0];
      u32 l = f2bf_rne(ldf(Wl,(long)c*COUT+k,f32m));
      u32 r = f2bf_rne(ldf(Wr,(long)c*COUT+k,f32m));
      v = (r<<16) | l;
    }
    out[i] = v;
  }
}

// ---------------- embedding: h0 = relu(x @ W + b), [100k,100]x[100,80] ----------------

__global__ __launch_bounds__(256) void k_embed(const void* __restrict__ x,
                                               const void* __restrict__ W,
                                               const void* __restrict__ b,
                                               const int* __restrict__ flags,
                                               float* __restrict__ h){
  __shared__ float Ws[100*80];
  const int f32m = flags[0];
  for(int i=threadIdx.x;i<100*80;i+=256) Ws[i]=ldf(W,i,f32m);
  __syncthreads();
  long tid = (long)blockIdx.x*256 + threadIdx.x;   // exactly N_NODES*80 threads
  int i = (int)(tid/80), k = (int)(tid%80);
  float acc = ldf(b,k,f32m);
  #pragma unroll 4
  for(int c=0;c<100;c++) acc = fmaf(ldf(x,(long)i*100+c,f32m), Ws[c*80+k], acc);
  h[(long)i*80+k] = fmaxf(acc, 0.f);
}

// ---------------- fused SAGE layer (LDS-free) ----------------
// one wave per node. Gather: 64-edge index batches + shfl broadcast, 4-way
// unrolled ILP. Matvec: fully unrolled, shfl-broadcast agg/h, packed bf16
// weight pairs from global (L1/L2 resident). L2 normalize, relu, store.

template<int CIN, int COUT, bool LAST>
__global__ __launch_bounds__(256,4) void k_sage(
    const float* __restrict__ hin, const int* __restrict__ off,
    const int* __restrict__ csr_src, const float* __restrict__ csr_ew,
    const u32* __restrict__ Wp, const void* __restrict__ bias,
    const int* __restrict__ flags, float* __restrict__ hout, void* __restrict__ outp)
{
  const int f32m = flags[0];
  const int lane = threadIdx.x&63;
  const int node = blockIdx.x*4 + (threadIdx.x>>6);   // grid covers N_NODES exactly
  constexpr int NC = (CIN+63)/64;                     // 1 (64ch) or 2 (80ch)

  float hreg[NC];
  const float* hr = hin + (long)node*CIN;
  #pragma unroll
  for(int u=0;u<NC;u++){
    int c = lane + 64*u;
    hreg[u] = (c<CIN) ? hr[c] : 0.f;
  }

  float a0[NC], a1[NC], a2[NC], a3[NC];
  #pragma unroll
  for(int u=0;u<NC;u++){ a0[u]=0.f; a1[u]=0.f; a2[u]=0.f; a3[u]=0.f; }

  const int e0 = off[node], e1 = off[node+1];
  for(int base=e0; base<e1; base+=64){
    const int cnt = min(64, e1-base);
    int   sv = (lane<cnt) ? csr_src[base+lane] : 0;
    float wv = 0.f;
    if(LAST) wv = 1.f;
    else     wv = (lane<cnt) ? csr_ew[base+lane] : 0.f;
    int j=0;
    for(; j+4<=cnt; j+=4){
      int   s0=__shfl(sv,j),   s1=__shfl(sv,j+1),   s2=__shfl(sv,j+2),   s3=__shfl(sv,j+3);
      float w0=__shfl(wv,j),   w1=__shfl(wv,j+1),   w2=__shfl(wv,j+2),   w3=__shfl(wv,j+3);
      const float* r0 = hin + (long)s0*CIN;
      const float* r1 = hin + (long)s1*CIN;
      const float* r2 = hin + (long)s2*CIN;
      const float* r3 = hin + (long)s3*CIN;
      #pragma unroll
      for(int u=0;u<NC;u++){
        int c = lane + 64*u;
        if(c<CIN){
          float x0=r0[c], x1=r1[c], x2=r2[c], x3=r3[c];
          a0[u]=fmaf(w0,x0,a0[u]); a1[u]=fmaf(w1,x1,a1[u]);
          a2[u]=fmaf(w2,x2,a2[u]); a3[u]=fmaf(w3,x3,a3[u]);
        }
      }
    }
    for(; j<cnt; j++){
      int s=__shfl(sv,j); float w=__shfl(wv,j);
      const float* r = hin + (long)s*CIN;
      #pragma unroll
      for(int u=0;u<NC;u++){
        int c = lane + 64*u;
        if(c<CIN) a0[u]=fmaf(w,r[c],a0[u]);
      }
    }
  }

  const float inv = 1.f/fmaxf((float)(e1-e0), 1.f);
  float aggv[NC];
  #pragma unroll
  for(int u=0;u<NC;u++) aggv[u] = ((a0[u]+a1[u])+(a2[u]+a3[u]))*inv;

  // matvec: o[lane] = bias[lane] + sum_c agg[c]*Wl[c][lane] + h[c]*Wr[c][lane]
  float o = (lane<COUT) ? ldf(bias,lane,f32m) : 0.f;
  #pragma unroll
  for(int c=0;c<CIN;c++){
    float ag = __shfl(aggv[c>>6], c&63);
    float hv = __shfl(hreg[c>>6], c&63);
    u32 p = Wp[(c<<6)|lane];               // zero-padded to 64 lanes, no OOB
    o = fmaf(ag, __uint_as_float(p<<16), o);
    o = fmaf(hv, __uint_as_float(p & 0xffff0000u), o);
  }

  float sq = o*o;                          // lanes >= COUT contribute 0
  #pragma unroll
  for(int d=1; d<64; d<<=1) sq += __shfl_xor(sq, d);
  float r = o * (1.f/fmaxf(sqrtf(sq), 1e-12f));
  if(!LAST) r = fmaxf(r, 0.f);

  if(lane<COUT){
    long oi = (long)node*COUT+lane;
    if(LAST){
      if(f32m) ((float*)outp)[oi] = r;
      else     ((bf16*)outp)[oi]  = __float2bfloat16(r);
    } else {
      hout[oi] = r;
    }
  }
}

// ---------------- launch ----------------

extern "C" void kernel_launch(void* const* d_in, const int* in_sizes, int n_in,
                              void* d_out, int out_size, void* d_ws, size_t ws_size,
                              hipStream_t stream){
  const void* x    = d_in[0];
  const int*  ei   = (const int*)d_in[1];
  const void* ew   = d_in[2];
  const void* embW = d_in[3];
  const void* embB = d_in[4];
  const void *Wl0=d_in[5],  *Wr0=d_in[6],  *b0=d_in[7];
  const void *Wl1=d_in[8],  *Wr1=d_in[9],  *b1=d_in[10];
  const void *Wl2=d_in[11], *Wr2=d_in[12], *b2=d_in[13];
  const void *Wl3=d_in[14], *Wr3=d_in[15], *b3=d_in[16];
  const void *Wlo=d_in[17], *Wro=d_in[18], *bo=d_in[19];

  char* w = (char*)d_ws;
  int*   flags   = (int*)w;   w += 16;
  int*   deg     = (int*)w;   w += (size_t)N_NODES*4;
  int*   cur     = (int*)w;   w += (size_t)N_NODES*4;
  int*   off     = (int*)w;   w += (size_t)(N_NODES+1)*4 + 4;
  int*   csr_src = (int*)w;   w += (size_t)N_EDGES*4;
  float* csr_ew  = (float*)w; w += (size_t)N_EDGES*4;
  u32*   Wp0     = (u32*)w;   w += (size_t)80*64*4;
  u32*   Wp1     = (u32*)w;   w += (size_t)64*64*4;
  u32*   Wp2     = (u32*)w;   w += (size_t)64*64*4;
  u32*   Wp3     = (u32*)w;   w += (size_t)64*64*4;
  u32*   Wpo     = (u32*)w;   w += (size_t)64*64*4;
  float* hA      = (float*)w; w += (size_t)N_NODES*80*4;   // stride 80 (layer0 in), reused stride 64 later
  float* hB      = (float*)w;                              // stride 64

  k_detect<<<1, 256, 0, stream>>>((const u32*)x, ei, flags);
  k_zero2<<<(N_NODES+255)/256, 256, 0, stream>>>(deg, cur);
  k_count<<<N_EDGES/256, 256, 0, stream>>>(ei, flags, deg);
  k_scan <<<1, 1024, 0, stream>>>(deg, off);
  k_fill <<<N_EDGES/256, 256, 0, stream>>>(ei, ew, flags, off, cur, csr_src, csr_ew);

  k_pack<<<20, 256, 0, stream>>>(Wl0, Wr0, flags, 80, 64, Wp0);
  k_pack<<<16, 256, 0, stream>>>(Wl1, Wr1, flags, 64, 64, Wp1);
  k_pack<<<16, 256, 0, stream>>>(Wl2, Wr2, flags, 64, 64, Wp2);
  k_pack<<<16, 256, 0, stream>>>(Wl3, Wr3, flags, 64, 64, Wp3);
  k_pack<<<16, 256, 0, stream>>>(Wlo, Wro, flags, 64, 18, Wpo);

  k_embed<<<(N_NODES*80)/256, 256, 0, stream>>>(x, embW, embB, flags, hA);

  k_sage<80,64,false><<<N_NODES/4, 256, 0, stream>>>(hA, off, csr_src, csr_ew, Wp0, b0, flags, hB, nullptr);
  k_sage<64,64,false><<<N_NODES/4, 256, 0, stream>>>(hB, off, csr_src, csr_ew, Wp1, b1, flags, hA, nullptr);
  k_sage<64,64,false><<<N_NODES/4, 256, 0, stream>>>(hA, off, csr_src, csr_ew, Wp2, b2, flags, hB, nullptr);
  k_sage<64,64,false><<<N_NODES/4, 256, 0, stream>>>(hB, off, csr_src, csr_ew, Wp3, b3, flags, hA, nullptr);
  k_sage<64,18,true ><<<N_NODES/4, 256, 0, stream>>>(hA, off, csr_src, csr_ew, Wpo, bo, flags, nullptr, d_out);
}

// Round 9
// 1288.556 us; speedup vs baseline: 2.3957x; 1.2470x over previous
//
#include <hip/hip_runtime.h>
#include <hip/hip_bf16.h>

#define N_NODES 100000
#define N_EDGES 1600000

using bf16 = __hip_bfloat16;
typedef unsigned int u32;

static __device__ __forceinline__ float b2f(bf16 v){ return __bfloat162float(v); }

// float loader: f32m=1 -> buffer is float32, f32m=0 -> buffer is bf16
static __device__ __forceinline__ float ldf(const void* p, long i, int f32m){
  return f32m ? ((const float*)p)[i] : b2f(((const bf16*)p)[i]);
}

static __device__ __forceinline__ u32 f2bf_rne(float f){
  u32 b = __float_as_uint(f);
  return (b + 0x7fffu + ((b>>16)&1u)) >> 16;
}

static __device__ __forceinline__ float pick4(float a, float b, float c, float d, int m){
  return m==0 ? a : (m==1 ? b : (m==2 ? c : d));
}

// ---------------- dtype detection (device-side, deterministic) ----------------
__global__ void k_detect(const u32* __restrict__ xw, const int* __restrict__ eiw,
                         int* __restrict__ flags){
  __shared__ int s_wild, s_nzodd;
  if(threadIdx.x==0){ s_wild=0; s_nzodd=0; }
  __syncthreads();
  int wild=0, nz=0;
  for(int k=threadIdx.x;k<2048;k+=256){
    u32 w  = xw[k];
    u32 lo = w & 0xffffu;
    int e  = (int)((lo>>7)&0xffu);
    if((lo & 0x7fffu)!=0u && (e<90 || e>160)) wild++;
    if(eiw[2*k+1]!=0) nz++;
  }
  atomicAdd(&s_wild, wild);
  atomicAdd(&s_nzodd, nz);
  __syncthreads();
  if(threadIdx.x==0){
    flags[0] = (s_wild > 512) ? 1 : 0;   // 1: floats are f32
    flags[1] = (s_nzodd == 0) ? 1 : 0;   // 1: indices are int64
  }
}

__global__ void k_zero2(int* __restrict__ a, int* __restrict__ b){
  int i = blockIdx.x*256 + threadIdx.x;
  if(i<N_NODES){ a[i]=0; b[i]=0; }
}

// ---------------- CSR build ----------------

__global__ void k_count(const int* __restrict__ ei, const int* __restrict__ flags,
                        int* __restrict__ deg){
  int e = blockIdx.x*256 + threadIdx.x;
  int i64 = flags[1];
  if(e < N_EDGES){
    long di = i64 ? 2l*(N_EDGES + e) : (long)(N_EDGES + e);
    atomicAdd(&deg[ei[di]], 1);
  }
}

__global__ void k_scan(const int* __restrict__ deg, int* __restrict__ off){
  __shared__ int sums[1024];
  __shared__ int base[1025];
  int t = threadIdx.x;
  const int chunk = (N_NODES + 1023)/1024;
  int b0 = t*chunk, b1 = min(b0+chunk, N_NODES);
  int s = 0;
  for(int i=b0;i<b1;i++) s += deg[i];
  sums[t] = s;
  __syncthreads();
  if(t==0){
    int acc=0;
    for(int i=0;i<1024;i++){ base[i]=acc; acc+=sums[i]; }
    base[1024]=acc;
  }
  __syncthreads();
  int acc = base[t];
  for(int i=b0;i<b1;i++){ off[i]=acc; acc+=deg[i]; }
  if(t==0) off[N_NODES] = base[1024];
}

__global__ void k_fill(const int* __restrict__ ei, const void* __restrict__ ew,
                       const int* __restrict__ flags, const int* __restrict__ off,
                       int* __restrict__ cur, int* __restrict__ csr_src,
                       float* __restrict__ csr_ew){
  int e = blockIdx.x*256 + threadIdx.x;
  int i64 = flags[1], f32m = flags[0];
  if(e < N_EDGES){
    int s = ei[i64 ? 2l*e : (long)e];
    int d = ei[i64 ? 2l*(N_EDGES+e) : (long)(N_EDGES+e)];
    int p = atomicAdd(&cur[d], 1);
    int idx = off[d] + p;
    csr_src[idx] = s;
    csr_ew[idx]  = ldf(ew, e, f32m);
  }
}

// ---------------- weight pre-pack: out[c*64+k] = {bf16(Wr), bf16(Wl)} ----------------

__global__ void k_pack(const void* __restrict__ Wl, const void* __restrict__ Wr,
                       const int* __restrict__ flags, int CIN, int COUT,
                       u32* __restrict__ out){
  int i = blockIdx.x*256 + threadIdx.x;
  if(i < CIN*64){
    int c = i>>6, k = i&63;
    u32 v = 0;
    if(k < COUT){
      int f32m = flags[0];
      u32 l = f2bf_rne(ldf(Wl,(long)c*COUT+k,f32m));
      u32 r = f2bf_rne(ldf(Wr,(long)c*COUT+k,f32m));
      v = (r<<16) | l;
    }
    out[i] = v;
  }
}

// ---------------- embedding: tiled LDS GEMM, 64 nodes/block, 4x5 reg tile ----------------

__global__ __launch_bounds__(256,2) void k_embed(const void* __restrict__ x,
                                                 const void* __restrict__ W,
                                                 const void* __restrict__ b,
                                                 const int* __restrict__ flags,
                                                 float* __restrict__ h){
  __shared__ float xs[100][65];     // [channel][node], pad 65 -> conflict-free
  __shared__ float Ws[100*80];
  const int t = threadIdx.x;
  const int n0 = blockIdx.x*64;
  const int f32m = flags[0];
  for(int i=t;i<8000;i+=256) Ws[i]=ldf(W,i,f32m);
  for(int idx=t; idx<6400; idx+=256){
    int n = idx/100, c = idx - n*100;
    float v = (n0+n < N_NODES) ? ldf(x,(long)(n0+n)*100+c,f32m) : 0.f;
    xs[c][n] = v;
  }
  __syncthreads();

  const int ng = t&15, og = t>>4;    // nodes ng*4..+3, outs og*5..+4
  float acc[4][5];
  #pragma unroll
  for(int j=0;j<5;j++){
    float bj = ldf(b, og*5+j, f32m);
    #pragma unroll
    for(int i=0;i<4;i++) acc[i][j] = bj;
  }
  #pragma unroll 2
  for(int c=0;c<100;c++){
    float xv[4];
    #pragma unroll
    for(int i=0;i<4;i++) xv[i] = xs[c][ng*4+i];
    #pragma unroll
    for(int j=0;j<5;j++){
      float wj = Ws[c*80+og*5+j];
      #pragma unroll
      for(int i=0;i<4;i++) acc[i][j] = fmaf(xv[i], wj, acc[i][j]);
    }
  }
  #pragma unroll
  for(int i=0;i<4;i++){
    int n = n0 + ng*4 + i;
    if(n < N_NODES){
      #pragma unroll
      for(int j=0;j<5;j++) h[(long)n*80 + og*5+j] = fmaxf(acc[i][j], 0.f);
    }
  }
}

// ---------------- fused SAGE layer (LDS-free, float4 row gather) ----------------
// one wave per node. Gather: CIN/4 lanes per edge read the neighbor row as
// float4 (4 edges/wave for CIN=64, 3 for CIN=80), 2 groups in flight.
// Cross-group shfl reduce + redistribute to lane=channel. Matvec: packed bf16
// weight pairs from global (L1-resident). L2 normalize, relu, store.
// NOTE: hin/hout MUST be 16B-aligned (ws carves are 256B-aligned).

template<int CIN, int COUT, bool LAST>
__global__ __launch_bounds__(256,4) void k_sage(
    const float* __restrict__ hin, const int* __restrict__ off,
    const int* __restrict__ csr_src, const float* __restrict__ csr_ew,
    const u32* __restrict__ Wp, const void* __restrict__ bias,
    const int* __restrict__ flags, float* __restrict__ hout, void* __restrict__ outp)
{
  const int f32m = flags[0];
  const int lane = threadIdx.x&63;
  const int node = blockIdx.x*4 + (threadIdx.x>>6);   // grid covers N_NODES exactly
  constexpr int NC  = (CIN+63)/64;                    // 1 (64ch) or 2 (80ch)
  constexpr int LPE = CIN/4;                          // lanes per edge-row: 16 or 20
  constexpr int EPW = 64/LPE;                         // edges per wave instr: 4 or 3

  const int sub = lane/LPE;                           // edge slot
  const int cl  = lane - sub*LPE;                     // float4-quad within row
  const bool lact = (sub < EPW);

  float hreg[NC];
  const float* hr = hin + (long)node*CIN;
  #pragma unroll
  for(int u=0;u<NC;u++){
    int c = lane + 64*u;
    hreg[u] = (c<CIN) ? hr[c] : 0.f;
  }

  float ax=0.f, ay=0.f, az=0.f, aw=0.f;
  const int e0 = off[node], e1 = off[node+1];
  for(int base=e0; base<e1; base+=64){
    const int cnt = min(64, e1-base);
    int   sv = (lane<cnt) ? csr_src[base+lane] : 0;
    float wv = LAST ? 1.f : ((lane<cnt) ? csr_ew[base+lane] : 0.f);
    for(int j=0; j<cnt; j+=2*EPW){
      int ei0 = j + sub, ei1 = j + EPW + sub;
      bool v0 = lact && (ei0 < cnt), v1 = lact && (ei1 < cnt);
      int x0i = v0 ? ei0 : 0, x1i = v1 ? ei1 : 0;
      int   s0 = __shfl(sv, x0i),  s1 = __shfl(sv, x1i);
      float w0 = __shfl(wv, x0i) * (v0 ? 1.f : 0.f);
      float w1 = __shfl(wv, x1i) * (v1 ? 1.f : 0.f);
      const float4 r0 = *(const float4*)(hin + (long)s0*CIN + 4*cl);
      const float4 r1 = *(const float4*)(hin + (long)s1*CIN + 4*cl);
      ax = fmaf(w0, r0.x, ax); ay = fmaf(w0, r0.y, ay);
      az = fmaf(w0, r0.z, az); aw = fmaf(w0, r0.w, aw);
      ax = fmaf(w1, r1.x, ax); ay = fmaf(w1, r1.y, ay);
      az = fmaf(w1, r1.z, az); aw = fmaf(w1, r1.w, aw);
    }
  }

  // cross-group reduce: every lane ends with full sum for its quad cl
  if(EPW == 4){
    ax += __shfl_xor(ax,16); ax += __shfl_xor(ax,32);
    ay += __shfl_xor(ay,16); ay += __shfl_xor(ay,32);
    az += __shfl_xor(az,16); az += __shfl_xor(az,32);
    aw += __shfl_xor(aw,16); aw += __shfl_xor(aw,32);
  } else {                       // EPW==3: groups at lanes 0..19 / 20..39 / 40..59
    ax = __shfl(ax,cl) + __shfl(ax,cl+20) + __shfl(ax,cl+40);
    ay = __shfl(ay,cl) + __shfl(ay,cl+20) + __shfl(ay,cl+40);
    az = __shfl(az,cl) + __shfl(az,cl+20) + __shfl(az,cl+40);
    aw = __shfl(aw,cl) + __shfl(aw,cl+20) + __shfl(aw,cl+40);
  }
  // now lane q (q<LPE) holds quad q channels [4q..4q+3]

  const float inv = 1.f/fmaxf((float)(e1-e0), 1.f);
  float aggv[NC];
  {
    int q = lane>>2, m = lane&3;
    float g0=__shfl(ax,q), g1=__shfl(ay,q), g2=__shfl(az,q), g3=__shfl(aw,q);
    aggv[0] = pick4(g0,g1,g2,g3,m) * inv;
    if(NC==2){
      int q2 = 16 + (lane>>2);   // channel lane+64, valid for lane<16
      float h0=__shfl(ax,q2), h1=__shfl(ay,q2), h2=__shfl(az,q2), h3=__shfl(aw,q2);
      aggv[1] = (lane<16) ? pick4(h0,h1,h2,h3,m) * inv : 0.f;
    }
  }

  // matvec: o[lane] = bias[lane] + sum_c agg[c]*Wl[c][lane] + h[c]*Wr[c][lane]
  float o = (lane<COUT) ? ldf(bias,lane,f32m) : 0.f;
  #pragma unroll
  for(int c=0;c<CIN;c++){
    float ag = __shfl(aggv[c>>6], c&63);
    float hv = __shfl(hreg[c>>6], c&63);
    u32 p = Wp[(c<<6)|lane];               // zero-padded to 64 lanes, no OOB
    o = fmaf(ag, __uint_as_float(p<<16), o);
    o = fmaf(hv, __uint_as_float(p & 0xffff0000u), o);
  }

  float sq = o*o;                          // lanes >= COUT contribute 0
  #pragma unroll
  for(int d=1; d<64; d<<=1) sq += __shfl_xor(sq, d);
  float r = o * (1.f/fmaxf(sqrtf(sq), 1e-12f));
  if(!LAST) r = fmaxf(r, 0.f);

  if(lane<COUT){
    long oi = (long)node*COUT+lane;
    if(LAST){
      if(f32m) ((float*)outp)[oi] = r;
      else     ((bf16*)outp)[oi]  = __float2bfloat16(r);
    } else {
      hout[oi] = r;
    }
  }
}

// ---------------- launch ----------------

extern "C" void kernel_launch(void* const* d_in, const int* in_sizes, int n_in,
                              void* d_out, int out_size, void* d_ws, size_t ws_size,
                              hipStream_t stream){
  const void* x    = d_in[0];
  const int*  ei   = (const int*)d_in[1];
  const void* ew   = d_in[2];
  const void* embW = d_in[3];
  const void* embB = d_in[4];
  const void *Wl0=d_in[5],  *Wr0=d_in[6],  *b0=d_in[7];
  const void *Wl1=d_in[8],  *Wr1=d_in[9],  *b1=d_in[10];
  const void *Wl2=d_in[11], *Wr2=d_in[12], *b2=d_in[13];
  const void *Wl3=d_in[14], *Wr3=d_in[15], *b3=d_in[16];
  const void *Wlo=d_in[17], *Wro=d_in[18], *bo=d_in[19];

  // 256B-aligned workspace carves (float4 gather targets must be 16B-aligned)
  char* w = (char*)d_ws;
  auto carve = [&](size_t nbytes)->char*{
    char* r = w; w += (nbytes + 255) & ~(size_t)255; return r;
  };
  int*   flags   = (int*)carve(16);
  int*   deg     = (int*)carve((size_t)N_NODES*4);
  int*   cur     = (int*)carve((size_t)N_NODES*4);
  int*   off     = (int*)carve((size_t)(N_NODES+1)*4);
  int*   csr_src = (int*)carve((size_t)N_EDGES*4);
  float* csr_ew  = (float*)carve((size_t)N_EDGES*4);
  u32*   Wp0     = (u32*)carve((size_t)80*64*4);
  u32*   Wp1     = (u32*)carve((size_t)64*64*4);
  u32*   Wp2     = (u32*)carve((size_t)64*64*4);
  u32*   Wp3     = (u32*)carve((size_t)64*64*4);
  u32*   Wpo     = (u32*)carve((size_t)64*64*4);
  float* hA      = (float*)carve((size_t)N_NODES*80*4);  // stride 80 (layer0 in), reused stride 64 later
  float* hB      = (float*)carve((size_t)N_NODES*64*4);  // stride 64

  k_detect<<<1, 256, 0, stream>>>((const u32*)x, ei, flags);
  k_zero2<<<(N_NODES+255)/256, 256, 0, stream>>>(deg, cur);
  k_count<<<N_EDGES/256, 256, 0, stream>>>(ei, flags, deg);
  k_scan <<<1, 1024, 0, stream>>>(deg, off);
  k_fill <<<N_EDGES/256, 256, 0, stream>>>(ei, ew, flags, off, cur, csr_src, csr_ew);

  k_pack<<<20, 256, 0, stream>>>(Wl0, Wr0, flags, 80, 64, Wp0);
  k_pack<<<16, 256, 0, stream>>>(Wl1, Wr1, flags, 64, 64, Wp1);
  k_pack<<<16, 256, 0, stream>>>(Wl2, Wr2, flags, 64, 64, Wp2);
  k_pack<<<16, 256, 0, stream>>>(Wl3, Wr3, flags, 64, 64, Wp3);
  k_pack<<<16, 256, 0, stream>>>(Wlo, Wro, flags, 64, 18, Wpo);

  k_embed<<<(N_NODES+63)/64, 256, 0, stream>>>(x, embW, embB, flags, hA);

  k_sage<80,64,false><<<N_NODES/4, 256, 0, stream>>>(hA, off, csr_src, csr_ew, Wp0, b0, flags, hB, nullptr);
  k_sage<64,64,false><<<N_NODES/4, 256, 0, stream>>>(hB, off, csr_src, csr_ew, Wp1, b1, flags, hA, nullptr);
  k_sage<64,64,false><<<N_NODES/4, 256, 0, stream>>>(hA, off, csr_src, csr_ew, Wp2, b2, flags, hB, nullptr);
  k_sage<64,64,false><<<N_NODES/4, 256, 0, stream>>>(hB, off, csr_src, csr_ew, Wp3, b3, flags, hA, nullptr);
  k_sage<64,18,true ><<<N_NODES/4, 256, 0, stream>>>(hA, off, csr_src, csr_ew, Wpo, bo, flags, nullptr, d_out);
}